// Round 4
// baseline (1118.275 us; speedup 1.0000x reference)
//
#include <hip/hip_runtime.h>

typedef __attribute__((ext_vector_type(8))) short short8;
typedef __attribute__((ext_vector_type(4))) float f32x4;

#define MFMA16(a, b, c) __builtin_amdgcn_mfma_f32_16x16x32_bf16((a), (b), (c), 0, 0, 0)

// fp32 -> bf16 (round-nearest-even), bit-level
static __device__ inline unsigned short f2bf(float f) {
    unsigned int u = __float_as_uint(f);
    u += 0x7fffu + ((u >> 16) & 1u);
    return (unsigned short)(u >> 16);
}

static __device__ inline ushort4 pack4(float4 x) {
    ushort4 r;
    r.x = f2bf(x.x); r.y = f2bf(x.y); r.z = f2bf(x.z); r.w = f2bf(x.w);
    return r;
}

// ---------------------------------------------------------------------------
// Kernel 1: QKV projections (unchanged — awaiting its own counters).
// Y[m][n] = sum_k X[m][k] * W[n][k] + bias[n]; M=8192, N=1024, K=1024, z picks GEMM.
// z=0 -> Qh (B,H,T,D) bf16 ; z=1 -> Kh (B,H,T,D) ; z=2 -> Vt (B,H,D,T)
// ---------------------------------------------------------------------------
__global__ __launch_bounds__(256) void qkv_proj_kernel(
    const float* __restrict__ q, const float* __restrict__ k, const float* __restrict__ v,
    const float* __restrict__ Wq, const float* __restrict__ bq,
    const float* __restrict__ Wk, const float* __restrict__ bk,
    const float* __restrict__ Wv, const float* __restrict__ bv,
    unsigned short* __restrict__ Qh, unsigned short* __restrict__ Kh,
    unsigned short* __restrict__ Vt)
{
    __shared__ unsigned short As[128][40];
    __shared__ unsigned short Bs[128][40];

    const int z = blockIdx.z;
    const float* X    = (z == 0) ? q  : (z == 1) ? k  : v;
    const float* W    = (z == 0) ? Wq : (z == 1) ? Wk : Wv;
    const float* bias = (z == 0) ? bq : (z == 1) ? bk : bv;

    const int m0 = blockIdx.y * 128;
    const int n0 = blockIdx.x * 128;
    const int tid = threadIdx.x;
    const int w = tid >> 6, lane = tid & 63, lr = lane & 15, lg = lane >> 4;
    const int wr = w >> 1, wc = w & 1;

    f32x4 acc[4][4];
    #pragma unroll
    for (int mi = 0; mi < 4; ++mi)
        #pragma unroll
        for (int ni = 0; ni < 4; ++ni) acc[mi][ni] = (f32x4){0.f, 0.f, 0.f, 0.f};

    for (int k0 = 0; k0 < 1024; k0 += 32) {
        #pragma unroll
        for (int i = 0; i < 4; ++i) {
            int vv = tid + 256 * i;
            int row = vv >> 3, c4 = vv & 7;
            float4 xa = *(const float4*)(X + (size_t)(m0 + row) * 1024 + k0 + c4 * 4);
            float4 xb = *(const float4*)(W + (size_t)(n0 + row) * 1024 + k0 + c4 * 4);
            *(ushort4*)&As[row][c4 * 4] = pack4(xa);
            *(ushort4*)&Bs[row][c4 * 4] = pack4(xb);
        }
        __syncthreads();
        short8 a[4], bf[4];
        #pragma unroll
        for (int mi = 0; mi < 4; ++mi) a[mi]  = *(const short8*)&As[wr * 64 + mi * 16 + lr][lg * 8];
        #pragma unroll
        for (int ni = 0; ni < 4; ++ni) bf[ni] = *(const short8*)&Bs[wc * 64 + ni * 16 + lr][lg * 8];
        #pragma unroll
        for (int mi = 0; mi < 4; ++mi)
            #pragma unroll
            for (int ni = 0; ni < 4; ++ni)
                acc[mi][ni] = MFMA16(a[mi], bf[ni], acc[mi][ni]);
        __syncthreads();
    }

    #pragma unroll
    for (int ni = 0; ni < 4; ++ni) {
        int n = n0 + wc * 64 + ni * 16 + lr;
        float bb = bias[n];
        int h = n >> 6, d = n & 63;
        #pragma unroll
        for (int mi = 0; mi < 4; ++mi) {
            #pragma unroll
            for (int r = 0; r < 4; ++r) {
                int m = m0 + wr * 64 + mi * 16 + lg * 4 + r;
                float val = acc[mi][ni][r] + bb;
                int bi = m >> 10, t = m & 1023;
                size_t hb = ((size_t)(bi * 16 + h)) << 16;
                if (z == 0)      Qh[hb + (size_t)t * 64 + d] = f2bf(val);
                else if (z == 1) Kh[hb + (size_t)t * 64 + d] = f2bf(val);
                else             Vt[hb + (size_t)d * 1024 + t] = f2bf(val);
            }
        }
    }
}

// ---------------------------------------------------------------------------
// Kernel 2: attention, SWAPPED-OPERAND QK^T.
// acc = mfma(K_frag, Q_frag): C[col = q-row = lane&15][row = kpos = lg*4+r].
// Each lane owns ONE q-row (lr) and 4 consecutive k-cols per acc quad ->
// int4 mask loads, float4 attn stores, ds_write_b64 P writes, 2-shuffle reduce.
// ---------------------------------------------------------------------------
__global__ __launch_bounds__(256) void attn_kernel(
    const unsigned short* __restrict__ Qh, const unsigned short* __restrict__ Kh,
    const unsigned short* __restrict__ Vt, const int* __restrict__ mask,
    float* __restrict__ attn, unsigned short* __restrict__ ctx)
{
    __shared__ unsigned short pb[16][1040];   // row stride 2080 B (16B-aligned)
    __shared__ float redA[16][4];
    __shared__ float redB[16][4];

    const int qt = blockIdx.x;     // q-tile (0..63)
    const int bh = blockIdx.y;     // b*16+h (0..127)
    const int tid = threadIdx.x;
    const int w = tid >> 6, lane = tid & 63, lr = lane & 15, lg = lane >> 4;
    const int qrow0 = qt * 16;

    // Q fragments (B operand): col = q-row = lr, k-elems = lg*8..+8
    const unsigned short* Qbase = Qh + ((size_t)bh << 16) + (size_t)qrow0 * 64;
    short8 bq0 = *(const short8*)(Qbase + (size_t)lr * 64 + lg * 8);
    short8 bq1 = *(const short8*)(Qbase + (size_t)lr * 64 + 32 + lg * 8);

    // scores: wave w covers kpos [256w, 256w+256)
    f32x4 acc[16];
    const unsigned short* Kbase = Kh + ((size_t)bh << 16) + (size_t)(w * 256) * 64;
    #pragma unroll
    for (int nt = 0; nt < 16; ++nt) {
        f32x4 c = {0.f, 0.f, 0.f, 0.f};
        const unsigned short* kp = Kbase + (size_t)(nt * 16 + lr) * 64 + lg * 8;
        short8 k0 = *(const short8*)kp;
        short8 k1 = *(const short8*)(kp + 32);
        c = MFMA16(k0, bq0, c);   // A = K (rows = kpos), B = Q (cols = q-rows)
        c = MFMA16(k1, bq1, c);
        acc[nt] = c;
    }
    // acc[nt][r] = S[kpos = w*256 + nt*16 + lg*4 + r][q = lr]

    const int qr = qrow0 + lr;
    const int colbase = w * 256 + lg * 4;
    const int* mrow = mask + (size_t)qr * 1024 + colbase;

    // scale + mask + per-lane max (lane owns q-row lr, 64 of its columns)
    float pm = -3.4e38f;
    #pragma unroll
    for (int nt = 0; nt < 16; ++nt) {
        int4 mv = *(const int4*)(mrow + nt * 16);
        float s0 = acc[nt][0] * 0.125f, s1 = acc[nt][1] * 0.125f;
        float s2 = acc[nt][2] * 0.125f, s3 = acc[nt][3] * 0.125f;
        acc[nt][0] = (mv.x == 0) ? -1.0e9f : s0;
        acc[nt][1] = (mv.y == 0) ? -1.0e9f : s1;
        acc[nt][2] = (mv.z == 0) ? -1.0e9f : s2;
        acc[nt][3] = (mv.w == 0) ? -1.0e9f : s3;
        pm = fmaxf(pm, fmaxf(fmaxf(acc[nt][0], acc[nt][1]), fmaxf(acc[nt][2], acc[nt][3])));
    }
    // across the 4 lane-groups holding the same q-row: lanes lr, lr+16, lr+32, lr+48
    pm = fmaxf(pm, __shfl_xor(pm, 16));
    pm = fmaxf(pm, __shfl_xor(pm, 32));
    if (lg == 0) redA[lr][w] = pm;
    __syncthreads();
    float rowm = fmaxf(fmaxf(redA[lr][0], redA[lr][1]), fmaxf(redA[lr][2], redA[lr][3]));

    // exp + per-lane sum
    float ps = 0.f;
    #pragma unroll
    for (int nt = 0; nt < 16; ++nt) {
        #pragma unroll
        for (int r = 0; r < 4; ++r) {
            float p = __expf(acc[nt][r] - rowm);
            acc[nt][r] = p;
            ps += p;
        }
    }
    ps += __shfl_xor(ps, 16);
    ps += __shfl_xor(ps, 32);
    if (lg == 0) redB[lr][w] = ps;
    __syncthreads();
    float inv = 1.0f / ((redB[lr][0] + redB[lr][1]) + (redB[lr][2] + redB[lr][3]));

    // write attn (float4) + P bf16 to LDS (ds_write_b64)
    float* arow = attn + ((size_t)bh << 20) + (size_t)qr * 1024 + colbase;
    #pragma unroll
    for (int nt = 0; nt < 16; ++nt) {
        float4 av;
        av.x = acc[nt][0] * inv; av.y = acc[nt][1] * inv;
        av.z = acc[nt][2] * inv; av.w = acc[nt][3] * inv;
        *(float4*)(arow + nt * 16) = av;
        *(ushort4*)&pb[lr][colbase + nt * 16] = pack4(av);
    }
    __syncthreads();

    // PV: ctx(16 x 64) = P(16 x 1024) @ V(1024 x 64); wave w -> d cols [16w,16w+16)
    f32x4 co = {0.f, 0.f, 0.f, 0.f};
    const unsigned short* Vbase = Vt + ((size_t)bh << 16) + (size_t)(w * 16) * 1024;
    #pragma unroll 8
    for (int ks = 0; ks < 32; ++ks) {
        short8 ap  = *(const short8*)&pb[lr][ks * 32 + lg * 8];
        short8 bv_ = *(const short8*)(Vbase + (size_t)lr * 1024 + ks * 32 + lg * 8);
        co = MFMA16(ap, bv_, co);
    }
    unsigned short* cb = ctx + ((size_t)(bh >> 4) * 1024 + qrow0) * 1024 + (size_t)(bh & 15) * 64;
    #pragma unroll
    for (int r = 0; r < 4; ++r)
        cb[(size_t)(lg * 4 + r) * 1024 + w * 16 + lr] = f2bf(co[r]);
}

// ---------------------------------------------------------------------------
// Kernel 2.5: convert Wo (64x1024 fp32) -> bf16 once, into the dead Qh buffer.
// ---------------------------------------------------------------------------
__global__ __launch_bounds__(256) void wo_cvt_kernel(
    const float* __restrict__ Wo, unsigned short* __restrict__ wob)
{
    int i = (blockIdx.x * 256 + threadIdx.x) * 4;   // 65536 elems / 4 = 16384 threads
    float4 x = *(const float4*)(Wo + i);
    *(ushort4*)(wob + i) = pack4(x);
}

// ---------------------------------------------------------------------------
// Kernel 3: out = ctx (8192x1024 bf16) @ Wo.T (1024x64, pre-cvt bf16) + bo.
// ---------------------------------------------------------------------------
__global__ __launch_bounds__(256) void oproj_kernel(
    const unsigned short* __restrict__ ctx, const unsigned short* __restrict__ wob,
    const float* __restrict__ bo, float* __restrict__ out)
{
    const int m0 = blockIdx.x * 64;
    const int tid = threadIdx.x;
    const int w = tid >> 6, lane = tid & 63, lr = lane & 15, lg = lane >> 4;

    f32x4 acc[4];
    #pragma unroll
    for (int i = 0; i < 4; ++i) acc[i] = (f32x4){0.f, 0.f, 0.f, 0.f};

    const unsigned short* abase = ctx + (size_t)(m0 + w * 16 + lr) * 1024 + lg * 8;
    #pragma unroll 4
    for (int ks = 0; ks < 32; ++ks) {
        short8 a = *(const short8*)(abase + (size_t)ks * 32);
        #pragma unroll
        for (int nt = 0; nt < 4; ++nt) {
            short8 b = *(const short8*)(wob + (size_t)(nt * 16 + lr) * 1024 + ks * 32 + lg * 8);
            acc[nt] = MFMA16(a, b, acc[nt]);
        }
    }
    #pragma unroll
    for (int nt = 0; nt < 4; ++nt) {
        int n = nt * 16 + lr;
        float bb = bo[n];
        #pragma unroll
        for (int r = 0; r < 4; ++r) {
            int m = m0 + w * 16 + lg * 4 + r;
            out[(size_t)m * 64 + n] = acc[nt][r] + bb;
        }
    }
}

// ---------------------------------------------------------------------------
extern "C" void kernel_launch(void* const* d_in, const int* in_sizes, int n_in,
                              void* d_out, int out_size, void* d_ws, size_t ws_size,
                              hipStream_t stream)
{
    (void)in_sizes; (void)n_in; (void)out_size; (void)ws_size;

    const float* q  = (const float*)d_in[0];
    const float* k  = (const float*)d_in[1];
    const float* v  = (const float*)d_in[2];
    const float* Wq = (const float*)d_in[3];
    const float* bq = (const float*)d_in[4];
    const float* Wk = (const float*)d_in[5];
    const float* bk = (const float*)d_in[6];
    const float* Wv = (const float*)d_in[7];
    const float* bv = (const float*)d_in[8];
    const float* Wo = (const float*)d_in[9];
    const float* bo = (const float*)d_in[10];
    const int* mask = (const int*)d_in[11];

    float* out  = (float*)d_out;
    float* attn = out + (size_t)8 * 1024 * 64;   // tuple order: (out, attn)

    // workspace: 4 x 16 MB bf16 buffers = 64 MB
    unsigned short* Qh  = (unsigned short*)d_ws;
    unsigned short* Kh  = Qh + (size_t)8388608;
    unsigned short* Vt  = Kh + (size_t)8388608;
    unsigned short* ctx = Vt + (size_t)8388608;
    unsigned short* wob = Qh;   // Qh is dead after attn_kernel; reuse for bf16 Wo

    qkv_proj_kernel<<<dim3(8, 64, 3), 256, 0, stream>>>(q, k, v, Wq, bq, Wk, bk, Wv, bv, Qh, Kh, Vt);
    attn_kernel<<<dim3(64, 128), 256, 0, stream>>>(Qh, Kh, Vt, mask, attn, ctx);
    wo_cvt_kernel<<<dim3(64), 256, 0, stream>>>(Wo, wob);
    oproj_kernel<<<dim3(128), 256, 0, stream>>>(ctx, wob, bo, out);
}